// Round 1
// baseline (351.933 us; speedup 1.0000x reference)
//
#include <hip/hip_runtime.h>
#include <hip/hip_bf16.h>
#include <stdint.h>

typedef __attribute__((ext_vector_type(8))) short bf16x8;
typedef __attribute__((ext_vector_type(4))) float f32x4;

__device__ __forceinline__ unsigned short f2bf(float f) {
  union { float f; uint32_t u; } v; v.f = f;
  uint32_t u = v.u;
  return (unsigned short)((u + 0x7fffu + ((u >> 16) & 1u)) >> 16);
}
__device__ __forceinline__ float bf2f(unsigned short h) {
  union { uint32_t u; float f; } v; v.u = ((uint32_t)h) << 16;
  return v.f;
}

// async global->LDS, 16B per lane; LDS dest must be wave-uniform base (+lane*16 implicit)
#define GLL(g, l) __builtin_amdgcn_global_load_lds( \
    (const __attribute__((address_space(1))) void*)(g), \
    (__attribute__((address_space(3))) void*)(l), 16, 0, 0)

// ---------------- fp32 -> bf16 converts ----------------
__global__ void cvt_x(const float* __restrict__ in, unsigned short* __restrict__ out) {
  const int i = (blockIdx.x * 256 + threadIdx.x) * 4;
  const float4 v = *(const float4*)(in + i);
  ushort4 o; o.x = f2bf(v.x); o.y = f2bf(v.y); o.z = f2bf(v.z); o.w = f2bf(v.w);
  *(ushort4*)(out + i) = o;
}

__global__ void cvt_w(const float* __restrict__ wk, const float* __restrict__ wq,
                      const float* __restrict__ wv, unsigned short* __restrict__ out) {
  const int i = (blockIdx.x * 256 + threadIdx.x) * 4;
  const float* src; int off;
  if (i < 65536)        { src = wk; off = i; }
  else if (i < 131072)  { src = wq; off = i - 65536; }
  else                  { src = wv; off = i - 131072; }
  const float4 v = *(const float4*)(src + off);
  ushort4 o; o.x = f2bf(v.x); o.y = f2bf(v.y); o.z = f2bf(v.z); o.w = f2bf(v.w);
  *(ushort4*)(out + i) = o;
}

// ---------------- QKV projection GEMM: C[m,n] = x[m,:]·W[n,:] + b[n] ----------------
// x_b [8192][512] bf16, w_b [768][512] bf16 (Wk|Wq|Wv rows). 128x128 tile, BK=64, 4 waves.
__global__ __launch_bounds__(256) void qkv_gemm(
    const unsigned short* __restrict__ xb, const unsigned short* __restrict__ wb,
    const float* __restrict__ pbk, const float* __restrict__ pbq, const float* __restrict__ pbv,
    unsigned short* __restrict__ kb, unsigned short* __restrict__ qb,
    unsigned short* __restrict__ vb, unsigned short* __restrict__ vtb)
{
  __shared__ unsigned short Alds[128 * 64];
  __shared__ unsigned short Blds[128 * 64];
  const int tid = threadIdx.x;
  const int lane = tid & 63;
  const int wid = tid >> 6;
  const int wm = wid >> 1, wn = wid & 1;
  const int m0 = blockIdx.x * 128, n0 = blockIdx.y * 128;
  const int l15 = lane & 15, l4 = lane >> 4;

  f32x4 acc[4][4] = {};

  for (int kt = 0; kt < 8; ++kt) {
    const int k0 = kt * 64;
    // stage A,B tiles [128][64] bf16; XOR-swizzle via pre-swizzled global source (rule #21)
    #pragma unroll
    for (int p = 0; p < 4; ++p) {
      const int e = p * 256 + tid;
      const int row = e >> 3;
      const int cs = (e & 7) ^ (row & 7);
      GLL(xb + (size_t)(m0 + row) * 512 + k0 + cs * 8, Alds + (p * 256 + (tid & ~63)) * 8);
      GLL(wb + (size_t)(n0 + row) * 512 + k0 + cs * 8, Blds + (p * 256 + (tid & ~63)) * 8);
    }
    __syncthreads();
    #pragma unroll
    for (int kk = 0; kk < 2; ++kk) {
      bf16x8 af[4], bfv[4];
      #pragma unroll
      for (int i = 0; i < 4; ++i) {
        const int ra = wm * 64 + i * 16 + l15;
        const int c  = kk * 4 + l4;
        af[i]  = *(const bf16x8*)(Alds + ra * 64 + ((c ^ (ra & 7)) * 8));
        const int rb = wn * 64 + i * 16 + l15;
        bfv[i] = *(const bf16x8*)(Blds + rb * 64 + ((c ^ (rb & 7)) * 8));
      }
      #pragma unroll
      for (int i = 0; i < 4; ++i)
        #pragma unroll
        for (int j = 0; j < 4; ++j)
          acc[i][j] = __builtin_amdgcn_mfma_f32_16x16x32_bf16(af[i], bfv[j], acc[i][j], 0, 0, 0);
    }
    __syncthreads();
  }

  // epilogue: bias add, route to k/q/v (+ v transposed for PV B-operand)
  #pragma unroll
  for (int i = 0; i < 4; ++i) {
    #pragma unroll
    for (int j = 0; j < 4; ++j) {
      const int rbase = m0 + wm * 64 + i * 16 + l4 * 4;
      const int c = n0 + wn * 64 + j * 16 + l15;
      const float bias = (c < 128) ? pbk[c] : (c < 256) ? pbq[c - 128] : pbv[c - 256];
      unsigned short o[4];
      #pragma unroll
      for (int r = 0; r < 4; ++r) o[r] = f2bf(acc[i][j][r] + bias);
      if (c < 128) {
        #pragma unroll
        for (int r = 0; r < 4; ++r) kb[(size_t)(rbase + r) * 128 + c] = o[r];
      } else if (c < 256) {
        #pragma unroll
        for (int r = 0; r < 4; ++r) qb[(size_t)(rbase + r) * 128 + (c - 128)] = o[r];
      } else {
        #pragma unroll
        for (int r = 0; r < 4; ++r) vb[(size_t)(rbase + r) * 512 + (c - 256)] = o[r];
        ushort4 t; t.x = o[0]; t.y = o[1]; t.z = o[2]; t.w = o[3];
        *(ushort4*)(vtb + (size_t)(c - 256) * 8192 + rbase) = t;
      }
    }
  }
}

// ---------------- fused scores + row-L2-norm + PV + residual ----------------
// Per block: 32 rows. S-phase: 8 waves each compute one 16x16 frag of S[32][64] (K=128),
// accumulate sum(S^2) per row in regs, write P=bf16(S) to LDS (XOR-swizzled).
// U-phase: wave w owns output cols [w*64, w*64+64); U += P @ V via vT B-fragments (L2-resident).
__global__ __launch_bounds__(512) void attn_fused(
    const unsigned short* __restrict__ kb, const unsigned short* __restrict__ qb,
    const unsigned short* __restrict__ vb, const unsigned short* __restrict__ vtb,
    float* __restrict__ out)
{
  __shared__ unsigned short Qlds[2][64 * 128];  // [64 rows][128 k] bf16, double-buffered
  __shared__ unsigned short Plds[32 * 64];      // [32 m][64 k] bf16
  __shared__ float ssq_part[4][32];
  __shared__ float rnorm_lds[32];

  const int tid = threadIdx.x, lane = tid & 63, wid = tid >> 6;
  const int smf = wid >> 2, snf = wid & 3;   // S fragment coords (2 x 4)
  const int m0 = blockIdx.x * 32;
  const int l15 = lane & 15, l4 = lane >> 4;

  // k A-fragments held in registers for the whole kernel (K=128 -> 4 MFMA k-steps)
  bf16x8 kfrag[4];
  {
    const size_t rowoff = (size_t)(m0 + smf * 16 + l15) * 128;
    #pragma unroll
    for (int kk = 0; kk < 4; ++kk)
      kfrag[kk] = *(const bf16x8*)(kb + rowoff + kk * 32 + l4 * 8);
  }

  float ssq[4] = {0.f, 0.f, 0.f, 0.f};
  f32x4 uacc[2][4] = {};

  // prologue: stage q tile j=0 into buffer 0 (pre-swizzled source, linear LDS dest)
  #pragma unroll
  for (int p = 0; p < 2; ++p) {
    const int e = p * 512 + tid;
    const int row = e >> 4;
    const int cs = (e & 15) ^ (row & 7);
    GLL(qb + (size_t)row * 128 + cs * 8, &Qlds[0][(p * 512 + (tid & ~63)) * 8]);
  }
  __syncthreads();

  for (int j = 0; j < 128; ++j) {
    const int cur = j & 1;

    // ---- S = k @ q^T (one 16x16 frag per wave) ----
    f32x4 sacc = {0.f, 0.f, 0.f, 0.f};
    {
      const int row = snf * 16 + l15;
      const unsigned short* qrow = &Qlds[cur][row * 128];
      #pragma unroll
      for (int kk = 0; kk < 4; ++kk) {
        const int c = kk * 4 + l4;
        const bf16x8 qf = *(const bf16x8*)(qrow + ((c ^ (row & 7)) * 8));
        sacc = __builtin_amdgcn_mfma_f32_16x16x32_bf16(kfrag[kk], qf, sacc, 0, 0, 0);
      }
    }
    // ---- sum-of-squares (fp32) + P write (bf16, swizzled) ----
    {
      const int prow0 = smf * 16 + l4 * 4;
      const int pcol = snf * 16 + l15;
      #pragma unroll
      for (int r = 0; r < 4; ++r) {
        const float s = sacc[r];
        ssq[r] += s * s;
        const int prow = prow0 + r;
        *(unsigned short*)((char*)Plds + prow * 128 + ((pcol * 2) ^ ((prow & 7) << 4))) = f2bf(s);
      }
    }
    __syncthreads();  // P visible; all waves done reading Qlds[cur^1] (since prev iter)

    // ---- issue next q-tile stage; latency hides under PV compute ----
    if (j < 127) {
      #pragma unroll
      for (int p = 0; p < 2; ++p) {
        const int e = p * 512 + tid;
        const int row = e >> 4;
        const int cs = (e & 15) ^ (row & 7);
        GLL(qb + (size_t)((j + 1) * 64 + row) * 128 + cs * 8,
            &Qlds[cur ^ 1][(p * 512 + (tid & ~63)) * 8]);
      }
    }

    // ---- U += P @ V (B-fragments straight from vT in L2/L3) ----
    #pragma unroll
    for (int kk2 = 0; kk2 < 2; ++kk2) {
      bf16x8 pf[2];
      #pragma unroll
      for (int mf2 = 0; mf2 < 2; ++mf2) {
        const int row = mf2 * 16 + l15;
        const int c = kk2 * 4 + l4;
        pf[mf2] = *(const bf16x8*)((const char*)Plds + row * 128 + ((c ^ (row & 7)) * 16));
      }
      #pragma unroll
      for (int nf2 = 0; nf2 < 4; ++nf2) {
        const int vcol = wid * 64 + nf2 * 16 + l15;
        const bf16x8 vf = *(const bf16x8*)(vtb + (size_t)vcol * 8192 + j * 64 + kk2 * 32 + l4 * 8);
        #pragma unroll
        for (int mf2 = 0; mf2 < 2; ++mf2)
          uacc[mf2][nf2] = __builtin_amdgcn_mfma_f32_16x16x32_bf16(pf[mf2], vf, uacc[mf2][nf2], 0, 0, 0);
      }
    }
    __syncthreads();  // U done (P free), staged q drained (vmcnt 0 at barrier)
  }

  // ---- row sum-of-squares: butterfly over the 16 col-lanes, then cross-wave in LDS ----
  #pragma unroll
  for (int d = 1; d < 16; d <<= 1)
    #pragma unroll
    for (int r = 0; r < 4; ++r) ssq[r] += __shfl_xor(ssq[r], d);
  if (l15 == 0) {
    #pragma unroll
    for (int r = 0; r < 4; ++r) ssq_part[snf][smf * 16 + l4 * 4 + r] = ssq[r];
  }
  __syncthreads();
  if (tid < 32) {
    const float s = ssq_part[0][tid] + ssq_part[1][tid] + ssq_part[2][tid] + ssq_part[3][tid];
    rnorm_lds[tid] = 1.0f / fmaxf(sqrtf(s), 1e-12f);
  }
  __syncthreads();

  // ---- epilogue: out = U * rnorm + v ----
  #pragma unroll
  for (int mf2 = 0; mf2 < 2; ++mf2) {
    #pragma unroll
    for (int nf2 = 0; nf2 < 4; ++nf2) {
      const int col = wid * 64 + nf2 * 16 + l15;
      #pragma unroll
      for (int r = 0; r < 4; ++r) {
        const int row = mf2 * 16 + l4 * 4 + r;
        const float u = uacc[mf2][nf2][r] * rnorm_lds[row];
        out[(size_t)(m0 + row) * 512 + col] = u + bf2f(vb[(size_t)(m0 + row) * 512 + col]);
      }
    }
  }
}

extern "C" void kernel_launch(void* const* d_in, const int* in_sizes, int n_in,
                              void* d_out, int out_size, void* d_ws, size_t ws_size,
                              hipStream_t stream) {
  const float* x  = (const float*)d_in[0];
  const float* Wk = (const float*)d_in[1];
  const float* bk = (const float*)d_in[2];
  const float* Wq = (const float*)d_in[3];
  const float* bq = (const float*)d_in[4];
  const float* Wv = (const float*)d_in[5];
  const float* bv = (const float*)d_in[6];
  float* out = (float*)d_out;

  char* ws = (char*)d_ws;
  unsigned short* xb  = (unsigned short*)(ws);              //  8192*512*2 = 8,388,608
  unsigned short* wb  = (unsigned short*)(ws + 8388608);    //   768*512*2 =   786,432
  unsigned short* kb  = (unsigned short*)(ws + 9175040);    //  8192*128*2 = 2,097,152
  unsigned short* qb  = (unsigned short*)(ws + 11272192);   //  8192*128*2 = 2,097,152
  unsigned short* vb  = (unsigned short*)(ws + 13369344);   //  8192*512*2 = 8,388,608
  unsigned short* vtb = (unsigned short*)(ws + 21757952);   //   512*8192*2= 8,388,608

  cvt_x<<<4096, 256, 0, stream>>>(x, xb);
  cvt_w<<<384, 256, 0, stream>>>(Wk, Wq, Wv, wb);
  qkv_gemm<<<dim3(64, 6), 256, 0, stream>>>(xb, wb, bk, bq, bv, kb, qb, vb, vtb);
  attn_fused<<<256, 512, 0, stream>>>(kb, qb, vb, vtb, out);
}

// Round 2
// 107.917 us; speedup vs baseline: 3.2611x; 3.2611x over previous
//
#include <hip/hip_runtime.h>
#include <hip/hip_bf16.h>
#include <stdint.h>

typedef __attribute__((ext_vector_type(8))) short bf16x8;
typedef __attribute__((ext_vector_type(4))) float f32x4;

__device__ __forceinline__ unsigned short f2bf(float f) {
  union { float f; uint32_t u; } v; v.f = f;
  uint32_t u = v.u;
  return (unsigned short)((u + 0x7fffu + ((u >> 16) & 1u)) >> 16);
}
__device__ __forceinline__ float bf2f(unsigned short h) {
  union { uint32_t u; float f; } v; v.u = ((uint32_t)h) << 16;
  return v.f;
}

#define GLL(g, l) __builtin_amdgcn_global_load_lds( \
    (const __attribute__((address_space(1))) void*)(g), \
    (__attribute__((address_space(3))) void*)(l), 16, 0, 0)

// ---------------- fp32 -> bf16 converts ----------------
__global__ void cvt_x(const float* __restrict__ in, unsigned short* __restrict__ out) {
  const int i = (blockIdx.x * 256 + threadIdx.x) * 4;
  const float4 v = *(const float4*)(in + i);
  ushort4 o; o.x = f2bf(v.x); o.y = f2bf(v.y); o.z = f2bf(v.z); o.w = f2bf(v.w);
  *(ushort4*)(out + i) = o;
}

__global__ void cvt_w(const float* __restrict__ wk, const float* __restrict__ wq,
                      const float* __restrict__ wv, unsigned short* __restrict__ out) {
  const int i = (blockIdx.x * 256 + threadIdx.x) * 4;
  const float* src; int off;
  if (i < 65536)        { src = wk; off = i; }
  else if (i < 131072)  { src = wq; off = i - 65536; }
  else                  { src = wv; off = i - 131072; }
  const float4 v = *(const float4*)(src + off);
  ushort4 o; o.x = f2bf(v.x); o.y = f2bf(v.y); o.z = f2bf(v.z); o.w = f2bf(v.w);
  *(ushort4*)(out + i) = o;
}

// ---------------- QKV projection GEMM: C[m,n] = x[m,:]·W[n,:] + b[n] ----------------
// x_b [8192][512] bf16, w_b [768][512] bf16 (Wk|Wq|Wv rows). 128x128 tile, BK=64, 4 waves.
// Outputs: kb [8192][128], qtb [128][8192] (q transposed), vb [8192][512], vtb [512][8192].
__global__ __launch_bounds__(256) void qkv_gemm(
    const unsigned short* __restrict__ xb, const unsigned short* __restrict__ wb,
    const float* __restrict__ pbk, const float* __restrict__ pbq, const float* __restrict__ pbv,
    unsigned short* __restrict__ kb, unsigned short* __restrict__ qtb,
    unsigned short* __restrict__ vb, unsigned short* __restrict__ vtb)
{
  __shared__ unsigned short Alds[128 * 64];
  __shared__ unsigned short Blds[128 * 64];
  const int tid = threadIdx.x;
  const int lane = tid & 63;
  const int wid = tid >> 6;
  const int wm = wid >> 1, wn = wid & 1;
  const int m0 = blockIdx.x * 128, n0 = blockIdx.y * 128;
  const int l15 = lane & 15, l4 = lane >> 4;

  f32x4 acc[4][4] = {};

  for (int kt = 0; kt < 8; ++kt) {
    const int k0 = kt * 64;
    #pragma unroll
    for (int p = 0; p < 4; ++p) {
      const int e = p * 256 + tid;
      const int row = e >> 3;
      const int cs = (e & 7) ^ (row & 7);
      GLL(xb + (size_t)(m0 + row) * 512 + k0 + cs * 8, Alds + (p * 256 + (tid & ~63)) * 8);
      GLL(wb + (size_t)(n0 + row) * 512 + k0 + cs * 8, Blds + (p * 256 + (tid & ~63)) * 8);
    }
    __syncthreads();
    #pragma unroll
    for (int kk = 0; kk < 2; ++kk) {
      bf16x8 af[4], bfv[4];
      #pragma unroll
      for (int i = 0; i < 4; ++i) {
        const int ra = wm * 64 + i * 16 + l15;
        const int c  = kk * 4 + l4;
        af[i]  = *(const bf16x8*)(Alds + ra * 64 + ((c ^ (ra & 7)) * 8));
        const int rb = wn * 64 + i * 16 + l15;
        bfv[i] = *(const bf16x8*)(Blds + rb * 64 + ((c ^ (rb & 7)) * 8));
      }
      #pragma unroll
      for (int i = 0; i < 4; ++i)
        #pragma unroll
        for (int j = 0; j < 4; ++j)
          acc[i][j] = __builtin_amdgcn_mfma_f32_16x16x32_bf16(af[i], bfv[j], acc[i][j], 0, 0, 0);
    }
    __syncthreads();
  }

  #pragma unroll
  for (int i = 0; i < 4; ++i) {
    #pragma unroll
    for (int j = 0; j < 4; ++j) {
      const int rbase = m0 + wm * 64 + i * 16 + l4 * 4;
      const int c = n0 + wn * 64 + j * 16 + l15;
      const float bias = (c < 128) ? pbk[c] : (c < 256) ? pbq[c - 128] : pbv[c - 256];
      unsigned short o[4];
      #pragma unroll
      for (int r = 0; r < 4; ++r) o[r] = f2bf(acc[i][j][r] + bias);
      if (c < 128) {
        #pragma unroll
        for (int r = 0; r < 4; ++r) kb[(size_t)(rbase + r) * 128 + c] = o[r];
      } else if (c < 256) {
        ushort4 t; t.x = o[0]; t.y = o[1]; t.z = o[2]; t.w = o[3];
        *(ushort4*)(qtb + (size_t)(c - 128) * 8192 + rbase) = t;
      } else {
        #pragma unroll
        for (int r = 0; r < 4; ++r) vb[(size_t)(rbase + r) * 512 + (c - 256)] = o[r];
        ushort4 t; t.x = o[0]; t.y = o[1]; t.z = o[2]; t.w = o[3];
        *(ushort4*)(vtb + (size_t)(c - 256) * 8192 + rbase) = t;
      }
    }
  }
}

// ---------------- [G|H] = Q^T [Q|V]  (split-K partials) ----------------
// grid (16 k-chunks, 4 col-quarters of 160), 512 thr. Wave w owns m-rows [w*16,+16), 10 n-frags.
// A^T[m=kq][g] = qtb, B^T[n][g] = qtb (n<128) else vtb. Partials [16][128][640] fp32.
__global__ __launch_bounds__(512) void gh_gemm(
    const unsigned short* __restrict__ qtb, const unsigned short* __restrict__ vtb,
    float* __restrict__ pbuf)
{
  const int tid = threadIdx.x, lane = tid & 63, wid = tid >> 6;
  const int l15 = lane & 15, l4 = lane >> 4;
  const int kc = blockIdx.x, nq = blockIdx.y;
  const int g0 = kc * 512;
  const int m0 = wid * 16;

  f32x4 acc[10] = {};

  #pragma unroll 2
  for (int ks = 0; ks < 16; ++ks) {
    const int g = g0 + ks * 32 + l4 * 8;
    const bf16x8 af = *(const bf16x8*)(qtb + (size_t)(m0 + l15) * 8192 + g);
    #pragma unroll
    for (int nf = 0; nf < 10; ++nf) {
      const int col = nq * 160 + nf * 16 + l15;
      const unsigned short* bp = (col < 128) ? (qtb + (size_t)col * 8192)
                                             : (vtb + (size_t)(col - 128) * 8192);
      const bf16x8 bf = *(const bf16x8*)(bp + g);
      acc[nf] = __builtin_amdgcn_mfma_f32_16x16x32_bf16(af, bf, acc[nf], 0, 0, 0);
    }
  }

  #pragma unroll
  for (int nf = 0; nf < 10; ++nf) {
    const int col = nq * 160 + nf * 16 + l15;
    #pragma unroll
    for (int r = 0; r < 4; ++r) {
      const int row = m0 + l4 * 4 + r;
      pbuf[((size_t)kc * 128 + row) * 640 + col] = acc[nf][r];
    }
  }
}

// Sum 16 partials -> Gb [128][128] bf16, Hbt [512][128] bf16 (H transposed).
__global__ void gh_finalize(const float* __restrict__ pbuf,
                            unsigned short* __restrict__ Gb, unsigned short* __restrict__ Hbt) {
  const int idx = blockIdx.x * 256 + threadIdx.x;  // 0..81919
  float s = 0.f;
  #pragma unroll
  for (int p = 0; p < 16; ++p) s += pbuf[(size_t)p * 81920 + idx];
  const int m = idx / 640, c = idx % 640;
  if (c < 128) Gb[m * 128 + c] = f2bf(s);
  else         Hbt[(size_t)(c - 128) * 128 + m] = f2bf(s);
}

// ---------------- rnorm: ssq_i = k_i G k_i^T via T = K·G then rowdot ----------------
// grid 64 blocks x 512 thr; wave w -> rows m0 + w*16.
__global__ __launch_bounds__(512) void tnorm(
    const unsigned short* __restrict__ kb, const unsigned short* __restrict__ Gb,
    float* __restrict__ rnorm)
{
  const int tid = threadIdx.x, lane = tid & 63, wid = tid >> 6;
  const int l15 = lane & 15, l4 = lane >> 4;
  const int rowbase = blockIdx.x * 128 + wid * 16;

  f32x4 acc[8] = {};
  #pragma unroll
  for (int ks = 0; ks < 4; ++ks) {
    const bf16x8 af = *(const bf16x8*)(kb + (size_t)(rowbase + l15) * 128 + ks * 32 + l4 * 8);
    #pragma unroll
    for (int nf = 0; nf < 8; ++nf) {
      // G symmetric: B^T[n][k] = G[n][k]
      const bf16x8 bf = *(const bf16x8*)(Gb + (size_t)(nf * 16 + l15) * 128 + ks * 32 + l4 * 8);
      acc[nf] = __builtin_amdgcn_mfma_f32_16x16x32_bf16(af, bf, acc[nf], 0, 0, 0);
    }
  }

  float ssq[4] = {0.f, 0.f, 0.f, 0.f};
  #pragma unroll
  for (int nf = 0; nf < 8; ++nf) {
    #pragma unroll
    for (int r = 0; r < 4; ++r) {
      const int row = rowbase + l4 * 4 + r;
      const float kv = bf2f(kb[(size_t)row * 128 + nf * 16 + l15]);
      ssq[r] += acc[nf][r] * kv;
    }
  }
  #pragma unroll
  for (int d = 1; d < 16; d <<= 1)
    #pragma unroll
    for (int r = 0; r < 4; ++r) ssq[r] += __shfl_xor(ssq[r], d);
  if (l15 == 0) {
    #pragma unroll
    for (int r = 0; r < 4; ++r) {
      const int row = rowbase + l4 * 4 + r;
      rnorm[row] = 1.0f / fmaxf(sqrtf(ssq[r]), 1e-12f);
    }
  }
}

// ---------------- out = (K·H) * rnorm + v ----------------
// grid 256 blocks of 32 rows; 512 thr; wave w: m-frag (w&1), col-quarter (w>>1).
__global__ __launch_bounds__(512) void uv_out(
    const unsigned short* __restrict__ kb, const unsigned short* __restrict__ Hbt,
    const float* __restrict__ rnorm, const unsigned short* __restrict__ vb,
    float* __restrict__ out)
{
  const int tid = threadIdx.x, lane = tid & 63, wid = tid >> 6;
  const int l15 = lane & 15, l4 = lane >> 4;
  const int m0 = blockIdx.x * 32;
  const int mf = wid & 1, nq = wid >> 1;
  const int rowbase = m0 + mf * 16;

  f32x4 acc[8] = {};
  #pragma unroll
  for (int ks = 0; ks < 4; ++ks) {
    const bf16x8 af = *(const bf16x8*)(kb + (size_t)(rowbase + l15) * 128 + ks * 32 + l4 * 8);
    #pragma unroll
    for (int nf = 0; nf < 8; ++nf) {
      const int col = nq * 128 + nf * 16 + l15;
      const bf16x8 bf = *(const bf16x8*)(Hbt + (size_t)col * 128 + ks * 32 + l4 * 8);
      acc[nf] = __builtin_amdgcn_mfma_f32_16x16x32_bf16(af, bf, acc[nf], 0, 0, 0);
    }
  }

  float rn[4];
  #pragma unroll
  for (int r = 0; r < 4; ++r) rn[r] = rnorm[rowbase + l4 * 4 + r];

  #pragma unroll
  for (int nf = 0; nf < 8; ++nf) {
    const int col = nq * 128 + nf * 16 + l15;
    #pragma unroll
    for (int r = 0; r < 4; ++r) {
      const int row = rowbase + l4 * 4 + r;
      out[(size_t)row * 512 + col] =
          acc[nf][r] * rn[r] + bf2f(vb[(size_t)row * 512 + col]);
    }
  }
}

extern "C" void kernel_launch(void* const* d_in, const int* in_sizes, int n_in,
                              void* d_out, int out_size, void* d_ws, size_t ws_size,
                              hipStream_t stream) {
  const float* x  = (const float*)d_in[0];
  const float* Wk = (const float*)d_in[1];
  const float* bk = (const float*)d_in[2];
  const float* Wq = (const float*)d_in[3];
  const float* bq = (const float*)d_in[4];
  const float* Wv = (const float*)d_in[5];
  const float* bv = (const float*)d_in[6];
  float* out = (float*)d_out;

  char* ws = (char*)d_ws;
  unsigned short* xb   = (unsigned short*)(ws);              //  8192*512*2 = 8,388,608
  unsigned short* wb   = (unsigned short*)(ws + 8388608);    //   768*512*2 =   786,432
  unsigned short* kb   = (unsigned short*)(ws + 9175040);    //  8192*128*2 = 2,097,152
  unsigned short* vb   = (unsigned short*)(ws + 11272192);   //  8192*512*2 = 8,388,608
  unsigned short* vtb  = (unsigned short*)(ws + 19660800);   //   512*8192*2= 8,388,608
  unsigned short* qtb  = (unsigned short*)(ws + 28049408);   //   128*8192*2= 2,097,152
  float*          pbuf = (float*)(ws + 30146560);            //  16*128*640*4=5,242,880
  unsigned short* Gb   = (unsigned short*)(ws + 35389440);   //   128*128*2 =    32,768
  unsigned short* Hbt  = (unsigned short*)(ws + 35422208);   //   512*128*2 =   131,072
  float*          rnm  = (float*)(ws + 35553280);            //   8192*4    =    32,768

  cvt_x<<<4096, 256, 0, stream>>>(x, xb);
  cvt_w<<<384, 256, 0, stream>>>(Wk, Wq, Wv, wb);
  qkv_gemm<<<dim3(64, 6), 256, 0, stream>>>(xb, wb, bk, bq, bv, kb, qtb, vb, vtb);
  gh_gemm<<<dim3(16, 4), 512, 0, stream>>>(qtb, vtb, pbuf);
  gh_finalize<<<320, 256, 0, stream>>>(pbuf, Gb, Hbt);
  tnorm<<<64, 512, 0, stream>>>(kb, Gb, rnm);
  uv_out<<<256, 512, 0, stream>>>(kb, Hbt, rnm, vb, out);
}

// Round 3
// 67.647 us; speedup vs baseline: 5.2025x; 1.5953x over previous
//
#include <hip/hip_runtime.h>
#include <hip/hip_bf16.h>
#include <stdint.h>

typedef __attribute__((ext_vector_type(8))) short bf16x8;
typedef __attribute__((ext_vector_type(4))) float f32x4;

__device__ __forceinline__ unsigned short f2bf(float f) {
  union { float f; uint32_t u; } v; v.f = f;
  uint32_t u = v.u;
  return (unsigned short)((u + 0x7fffu + ((u >> 16) & 1u)) >> 16);
}
__device__ __forceinline__ float bf2f(unsigned short h) {
  union { uint32_t u; float f; } v; v.u = ((uint32_t)h) << 16;
  return v.f;
}

#define GLL(g, l) __builtin_amdgcn_global_load_lds( \
    (const __attribute__((address_space(1))) void*)(g), \
    (__attribute__((address_space(3))) void*)(l), 16, 0, 0)

// ---------------- fp32 -> bf16 converts ----------------
__global__ void cvt_x(const float* __restrict__ in, unsigned short* __restrict__ out) {
  const int i = (blockIdx.x * 256 + threadIdx.x) * 4;
  const float4 v = *(const float4*)(in + i);
  ushort4 o; o.x = f2bf(v.x); o.y = f2bf(v.y); o.z = f2bf(v.z); o.w = f2bf(v.w);
  *(ushort4*)(out + i) = o;
}

__global__ void cvt_w(const float* __restrict__ wk, const float* __restrict__ wq,
                      const float* __restrict__ wv, unsigned short* __restrict__ out) {
  const int i = (blockIdx.x * 256 + threadIdx.x) * 4;
  const float* src; int off;
  if (i < 65536)        { src = wk; off = i; }
  else if (i < 131072)  { src = wq; off = i - 65536; }
  else                  { src = wv; off = i - 131072; }
  const float4 v = *(const float4*)(src + off);
  ushort4 o; o.x = f2bf(v.x); o.y = f2bf(v.y); o.z = f2bf(v.z); o.w = f2bf(v.w);
  *(ushort4*)(out + i) = o;
}

// ---------------- QKV projection GEMM: C[m,n] = x[m,:]·W[n,:] + b[n] ----------------
// x_b [8192][512] bf16, w_b [768][512] bf16 (Wk|Wq|Wv rows). 128x128 tile, BK=64, 4 waves.
// Outputs: kb [8192][128], qtb [128][8192] (q transposed), vb [8192][512], vtb [512][8192].
__global__ __launch_bounds__(256) void qkv_gemm(
    const unsigned short* __restrict__ xb, const unsigned short* __restrict__ wb,
    const float* __restrict__ pbk, const float* __restrict__ pbq, const float* __restrict__ pbv,
    unsigned short* __restrict__ kb, unsigned short* __restrict__ qtb,
    unsigned short* __restrict__ vb, unsigned short* __restrict__ vtb)
{
  __shared__ unsigned short Alds[128 * 64];
  __shared__ unsigned short Blds[128 * 64];
  const int tid = threadIdx.x;
  const int lane = tid & 63;
  const int wid = tid >> 6;
  const int wm = wid >> 1, wn = wid & 1;
  const int m0 = blockIdx.x * 128, n0 = blockIdx.y * 128;
  const int l15 = lane & 15, l4 = lane >> 4;

  f32x4 acc[4][4] = {};

  for (int kt = 0; kt < 8; ++kt) {
    const int k0 = kt * 64;
    #pragma unroll
    for (int p = 0; p < 4; ++p) {
      const int e = p * 256 + tid;
      const int row = e >> 3;
      const int cs = (e & 7) ^ (row & 7);
      GLL(xb + (size_t)(m0 + row) * 512 + k0 + cs * 8, Alds + (p * 256 + (tid & ~63)) * 8);
      GLL(wb + (size_t)(n0 + row) * 512 + k0 + cs * 8, Blds + (p * 256 + (tid & ~63)) * 8);
    }
    __syncthreads();
    #pragma unroll
    for (int kk = 0; kk < 2; ++kk) {
      bf16x8 af[4], bfv[4];
      #pragma unroll
      for (int i = 0; i < 4; ++i) {
        const int ra = wm * 64 + i * 16 + l15;
        const int c  = kk * 4 + l4;
        af[i]  = *(const bf16x8*)(Alds + ra * 64 + ((c ^ (ra & 7)) * 8));
        const int rb = wn * 64 + i * 16 + l15;
        bfv[i] = *(const bf16x8*)(Blds + rb * 64 + ((c ^ (rb & 7)) * 8));
      }
      #pragma unroll
      for (int i = 0; i < 4; ++i)
        #pragma unroll
        for (int j = 0; j < 4; ++j)
          acc[i][j] = __builtin_amdgcn_mfma_f32_16x16x32_bf16(af[i], bfv[j], acc[i][j], 0, 0, 0);
    }
    __syncthreads();
  }

  #pragma unroll
  for (int i = 0; i < 4; ++i) {
    #pragma unroll
    for (int j = 0; j < 4; ++j) {
      const int rbase = m0 + wm * 64 + i * 16 + l4 * 4;
      const int c = n0 + wn * 64 + j * 16 + l15;
      const float bias = (c < 128) ? pbk[c] : (c < 256) ? pbq[c - 128] : pbv[c - 256];
      unsigned short o[4];
      #pragma unroll
      for (int r = 0; r < 4; ++r) o[r] = f2bf(acc[i][j][r] + bias);
      if (c < 128) {
        #pragma unroll
        for (int r = 0; r < 4; ++r) kb[(size_t)(rbase + r) * 128 + c] = o[r];
      } else if (c < 256) {
        ushort4 t; t.x = o[0]; t.y = o[1]; t.z = o[2]; t.w = o[3];
        *(ushort4*)(qtb + (size_t)(c - 128) * 8192 + rbase) = t;
      } else {
        #pragma unroll
        for (int r = 0; r < 4; ++r) vb[(size_t)(rbase + r) * 512 + (c - 256)] = o[r];
        ushort4 t; t.x = o[0]; t.y = o[1]; t.z = o[2]; t.w = o[3];
        *(ushort4*)(vtb + (size_t)(c - 256) * 8192 + rbase) = t;
      }
    }
  }
}

// ---------------- [G|H] = Q^T [Q|V]  (LDS-staged split-K) ----------------
// grid (kc=32 g-chunks of 256, nq=8 col-slices of 80), 512 thr (8 waves).
// A = Qt [128 m][g] (qtb), B^T[col][g] from qtb (col<128) / vtb. Partials bf16 [32][128][640].
__global__ __launch_bounds__(512) void gh_gemm(
    const unsigned short* __restrict__ qtb, const unsigned short* __restrict__ vtb,
    unsigned short* __restrict__ pb)
{
  __shared__ unsigned short Alds[128 * 64];  // [m 0..127][g 0..63] swizzled
  __shared__ unsigned short Blds[80 * 64];   // [col 0..79][g 0..63] swizzled
  const int tid = threadIdx.x, lane = tid & 63, wid = tid >> 6;
  const int l15 = lane & 15, l4 = lane >> 4;
  const int kc = blockIdx.x, nq = blockIdx.y;
  const int g0 = kc * 256;
  const int m0 = wid * 16;

  f32x4 acc[5] = {};

  for (int st = 0; st < 4; ++st) {
    const int gs = g0 + st * 64;
    // stage A: 1024 16B-chunks (128 rows x 8), 2 per thread
    #pragma unroll
    for (int p = 0; p < 2; ++p) {
      const int e = p * 512 + tid;
      const int row = e >> 3;
      const int cs = (e & 7) ^ (row & 7);
      GLL(qtb + (size_t)row * 8192 + gs + cs * 8, Alds + (p * 512 + (tid & ~63)) * 8);
    }
    // stage B: 640 chunks (80 rows x 8) = 512 + 128
    {
      const int row = tid >> 3;
      const int cglob = nq * 80 + row;
      const unsigned short* src = (cglob < 128) ? (qtb + (size_t)cglob * 8192)
                                                : (vtb + (size_t)(cglob - 128) * 8192);
      const int cs = (tid & 7) ^ (row & 7);
      GLL(src + gs + cs * 8, Blds + (tid & ~63) * 8);
    }
    if (tid < 128) {
      const int e = 512 + tid;
      const int row = e >> 3;
      const int cglob = nq * 80 + row;
      const unsigned short* src = (cglob < 128) ? (qtb + (size_t)cglob * 8192)
                                                : (vtb + (size_t)(cglob - 128) * 8192);
      const int cs = (e & 7) ^ (row & 7);
      GLL(src + gs + cs * 8, Blds + (512 + (tid & ~63)) * 8);
    }
    __syncthreads();
    #pragma unroll
    for (int ks = 0; ks < 2; ++ks) {
      const int ra = m0 + l15;
      const int ca = ks * 4 + l4;
      const bf16x8 af = *(const bf16x8*)(Alds + ra * 64 + ((ca ^ (ra & 7)) * 8));
      #pragma unroll
      for (int nf = 0; nf < 5; ++nf) {
        const int rb = nf * 16 + l15;
        const bf16x8 bf = *(const bf16x8*)(Blds + rb * 64 + ((ca ^ (rb & 7)) * 8));
        acc[nf] = __builtin_amdgcn_mfma_f32_16x16x32_bf16(af, bf, acc[nf], 0, 0, 0);
      }
    }
    __syncthreads();
  }

  #pragma unroll
  for (int nf = 0; nf < 5; ++nf) {
    const int col = nq * 80 + nf * 16 + l15;
    #pragma unroll
    for (int r = 0; r < 4; ++r) {
      const int row = m0 + l4 * 4 + r;
      pb[((size_t)kc * 128 + row) * 640 + col] = f2bf(acc[nf][r]);
    }
  }
}

// Sum 32 bf16 partials -> Gb [128][128] bf16, Hbt [512][128] bf16 (H transposed).
__global__ void gh_finalize(const unsigned short* __restrict__ pb,
                            unsigned short* __restrict__ Gb, unsigned short* __restrict__ Hbt) {
  const int idx = blockIdx.x * 256 + threadIdx.x;  // 0..81919
  float s = 0.f;
  #pragma unroll
  for (int p = 0; p < 32; ++p) s += bf2f(pb[(size_t)p * 81920 + idx]);
  const int m = idx / 640, c = idx % 640;
  if (c < 128) Gb[m * 128 + c] = f2bf(s);
  else         Hbt[(size_t)(c - 128) * 128 + m] = f2bf(s);
}

// ---------------- rnorm: ssq_i = k_i G k_i^T via T = K·G then rowdot ----------------
// grid 64 blocks x 512 thr; wave w -> rows m0 + w*16.
__global__ __launch_bounds__(512) void tnorm(
    const unsigned short* __restrict__ kb, const unsigned short* __restrict__ Gb,
    float* __restrict__ rnorm)
{
  const int tid = threadIdx.x, lane = tid & 63, wid = tid >> 6;
  const int l15 = lane & 15, l4 = lane >> 4;
  const int rowbase = blockIdx.x * 128 + wid * 16;

  f32x4 acc[8] = {};
  #pragma unroll
  for (int ks = 0; ks < 4; ++ks) {
    const bf16x8 af = *(const bf16x8*)(kb + (size_t)(rowbase + l15) * 128 + ks * 32 + l4 * 8);
    #pragma unroll
    for (int nf = 0; nf < 8; ++nf) {
      // G symmetric: B^T[n][k] = G[n][k]
      const bf16x8 bf = *(const bf16x8*)(Gb + (size_t)(nf * 16 + l15) * 128 + ks * 32 + l4 * 8);
      acc[nf] = __builtin_amdgcn_mfma_f32_16x16x32_bf16(af, bf, acc[nf], 0, 0, 0);
    }
  }

  float ssq[4] = {0.f, 0.f, 0.f, 0.f};
  #pragma unroll
  for (int nf = 0; nf < 8; ++nf) {
    #pragma unroll
    for (int r = 0; r < 4; ++r) {
      const int row = rowbase + l4 * 4 + r;
      const float kv = bf2f(kb[(size_t)row * 128 + nf * 16 + l15]);
      ssq[r] += acc[nf][r] * kv;
    }
  }
  #pragma unroll
  for (int d = 1; d < 16; d <<= 1)
    #pragma unroll
    for (int r = 0; r < 4; ++r) ssq[r] += __shfl_xor(ssq[r], d);
  if (l15 == 0) {
    #pragma unroll
    for (int r = 0; r < 4; ++r) {
      const int row = rowbase + l4 * 4 + r;
      rnorm[row] = 1.0f / fmaxf(sqrtf(ssq[r]), 1e-12f);
    }
  }
}

// ---------------- out = (K·H) * rnorm + v ----------------
// grid 256 blocks of 32 rows; 512 thr; wave w: m-frag (w&1), col-quarter (w>>1).
__global__ __launch_bounds__(512) void uv_out(
    const unsigned short* __restrict__ kb, const unsigned short* __restrict__ Hbt,
    const float* __restrict__ rnorm, const unsigned short* __restrict__ vb,
    float* __restrict__ out)
{
  const int tid = threadIdx.x, lane = tid & 63, wid = tid >> 6;
  const int l15 = lane & 15, l4 = lane >> 4;
  const int m0 = blockIdx.x * 32;
  const int mf = wid & 1, nq = wid >> 1;
  const int rowbase = m0 + mf * 16;

  f32x4 acc[8] = {};
  #pragma unroll
  for (int ks = 0; ks < 4; ++ks) {
    const bf16x8 af = *(const bf16x8*)(kb + (size_t)(rowbase + l15) * 128 + ks * 32 + l4 * 8);
    #pragma unroll
    for (int nf = 0; nf < 8; ++nf) {
      const int col = nq * 128 + nf * 16 + l15;
      const bf16x8 bf = *(const bf16x8*)(Hbt + (size_t)col * 128 + ks * 32 + l4 * 8);
      acc[nf] = __builtin_amdgcn_mfma_f32_16x16x32_bf16(af, bf, acc[nf], 0, 0, 0);
    }
  }

  float rn[4];
  #pragma unroll
  for (int r = 0; r < 4; ++r) rn[r] = rnorm[rowbase + l4 * 4 + r];

  #pragma unroll
  for (int nf = 0; nf < 8; ++nf) {
    const int col = nq * 128 + nf * 16 + l15;
    #pragma unroll
    for (int r = 0; r < 4; ++r) {
      const int row = rowbase + l4 * 4 + r;
      out[(size_t)row * 512 + col] =
          acc[nf][r] * rn[r] + bf2f(vb[(size_t)row * 512 + col]);
    }
  }
}

extern "C" void kernel_launch(void* const* d_in, const int* in_sizes, int n_in,
                              void* d_out, int out_size, void* d_ws, size_t ws_size,
                              hipStream_t stream) {
  const float* x  = (const float*)d_in[0];
  const float* Wk = (const float*)d_in[1];
  const float* bk = (const float*)d_in[2];
  const float* Wq = (const float*)d_in[3];
  const float* bq = (const float*)d_in[4];
  const float* Wv = (const float*)d_in[5];
  const float* bv = (const float*)d_in[6];
  float* out = (float*)d_out;

  char* ws = (char*)d_ws;
  unsigned short* xb   = (unsigned short*)(ws);              //  8192*512*2 = 8,388,608
  unsigned short* wb   = (unsigned short*)(ws + 8388608);    //   768*512*2 =   786,432
  unsigned short* kb   = (unsigned short*)(ws + 9175040);    //  8192*128*2 = 2,097,152
  unsigned short* vb   = (unsigned short*)(ws + 11272192);   //  8192*512*2 = 8,388,608
  unsigned short* vtb  = (unsigned short*)(ws + 19660800);   //   512*8192*2= 8,388,608
  unsigned short* qtb  = (unsigned short*)(ws + 28049408);   //   128*8192*2= 2,097,152
  unsigned short* pb   = (unsigned short*)(ws + 30146560);   //  32*128*640*2=5,242,880
  unsigned short* Gb   = (unsigned short*)(ws + 35389440);   //   128*128*2 =    32,768
  unsigned short* Hbt  = (unsigned short*)(ws + 35422208);   //   512*128*2 =   131,072
  float*          rnm  = (float*)(ws + 35553280);            //   8192*4    =    32,768

  cvt_x<<<4096, 256, 0, stream>>>(x, xb);
  cvt_w<<<384, 256, 0, stream>>>(Wk, Wq, Wv, wb);
  qkv_gemm<<<dim3(64, 6), 256, 0, stream>>>(xb, wb, bk, bq, bv, kb, qtb, vb, vtb);
  gh_gemm<<<dim3(32, 8), 512, 0, stream>>>(qtb, vtb, pb);
  gh_finalize<<<320, 256, 0, stream>>>(pb, Gb, Hbt);
  tnorm<<<64, 512, 0, stream>>>(kb, Gb, rnm);
  uv_out<<<256, 512, 0, stream>>>(kb, Hbt, rnm, vb, out);
}

// Round 4
// 53.228 us; speedup vs baseline: 6.6118x; 1.2709x over previous
//
#include <hip/hip_runtime.h>
#include <hip/hip_bf16.h>
#include <stdint.h>

typedef __attribute__((ext_vector_type(8))) short bf16x8;
typedef __attribute__((ext_vector_type(4))) float f32x4;

__device__ __forceinline__ unsigned short f2bf(float f) {
  union { float f; uint32_t u; } v; v.f = f;
  uint32_t u = v.u;
  return (unsigned short)((u + 0x7fffu + ((u >> 16) & 1u)) >> 16);
}
__device__ __forceinline__ float bf2f(unsigned short h) {
  union { uint32_t u; float f; } v; v.u = ((uint32_t)h) << 16;
  return v.f;
}

#define GLL(g, l) __builtin_amdgcn_global_load_lds( \
    (const __attribute__((address_space(1))) void*)(g), \
    (__attribute__((address_space(3))) void*)(l), 16, 0, 0)

// ---------------- fp32 -> bf16 convert (x and Wk|Wq|Wv in one launch) ----------------
__global__ void cvt_all(const float* __restrict__ x,
                        const float* __restrict__ wk, const float* __restrict__ wq,
                        const float* __restrict__ wv,
                        unsigned short* __restrict__ xb, unsigned short* __restrict__ wb) {
  const int i = (blockIdx.x * 256 + threadIdx.x) * 4;
  const float* src; unsigned short* dst; int off;
  if (i < 4194304) { src = x; dst = xb; off = i; }
  else {
    const int j = i - 4194304;
    dst = wb; 
    if (j < 65536)       { src = wk; off = j; }
    else if (j < 131072) { src = wq; off = j - 65536; }
    else                 { src = wv; off = j - 131072; }
    dst = wb + (j - off); // base shift so dst[off] lands at wb[j]
  }
  const float4 v = *(const float4*)(src + off);
  ushort4 o; o.x = f2bf(v.x); o.y = f2bf(v.y); o.z = f2bf(v.z); o.w = f2bf(v.w);
  *(ushort4*)(dst + off) = o;
}

// ---------------- QKV projection GEMM: C[m,n] = x[m,:]·W[n,:] + b[n] ----------------
// 128x128 tile, BK=64, 4 waves, double-buffered LDS (T3 minimum 2-phase).
__global__ __launch_bounds__(256) void qkv_gemm(
    const unsigned short* __restrict__ xb, const unsigned short* __restrict__ wb,
    const float* __restrict__ pbk, const float* __restrict__ pbq, const float* __restrict__ pbv,
    unsigned short* __restrict__ kb, unsigned short* __restrict__ qtb,
    unsigned short* __restrict__ vb, unsigned short* __restrict__ vtb)
{
  __shared__ unsigned short Alds[2][128 * 64];
  __shared__ unsigned short Blds[2][128 * 64];
  const int tid = threadIdx.x;
  const int lane = tid & 63;
  const int wid = tid >> 6;
  const int wm = wid >> 1, wn = wid & 1;
  const int m0 = blockIdx.x * 128, n0 = blockIdx.y * 128;
  const int l15 = lane & 15, l4 = lane >> 4;

  f32x4 acc[4][4] = {};

  auto stage = [&](int b, int kt) {
    const int k0 = kt * 64;
    #pragma unroll
    for (int p = 0; p < 4; ++p) {
      const int e = p * 256 + tid;
      const int row = e >> 3;
      const int cs = (e & 7) ^ (row & 7);
      GLL(xb + (size_t)(m0 + row) * 512 + k0 + cs * 8, &Alds[b][(p * 256 + (tid & ~63)) * 8]);
      GLL(wb + (size_t)(n0 + row) * 512 + k0 + cs * 8, &Blds[b][(p * 256 + (tid & ~63)) * 8]);
    }
  };

  stage(0, 0);
  __syncthreads();

  for (int kt = 0; kt < 8; ++kt) {
    const int cur = kt & 1;
    if (kt < 7) stage(cur ^ 1, kt + 1);  // async loads overlap compute below
    #pragma unroll
    for (int kk = 0; kk < 2; ++kk) {
      bf16x8 af[4], bfv[4];
      #pragma unroll
      for (int i = 0; i < 4; ++i) {
        const int ra = wm * 64 + i * 16 + l15;
        const int c  = kk * 4 + l4;
        af[i]  = *(const bf16x8*)(&Alds[cur][ra * 64 + ((c ^ (ra & 7)) * 8)]);
        const int rb = wn * 64 + i * 16 + l15;
        bfv[i] = *(const bf16x8*)(&Blds[cur][rb * 64 + ((c ^ (rb & 7)) * 8)]);
      }
      #pragma unroll
      for (int i = 0; i < 4; ++i)
        #pragma unroll
        for (int j = 0; j < 4; ++j)
          acc[i][j] = __builtin_amdgcn_mfma_f32_16x16x32_bf16(af[i], bfv[j], acc[i][j], 0, 0, 0);
    }
    __syncthreads();  // drains vmcnt(0): next buf staged; all waves done with cur
  }

  #pragma unroll
  for (int i = 0; i < 4; ++i) {
    #pragma unroll
    for (int j = 0; j < 4; ++j) {
      const int rbase = m0 + wm * 64 + i * 16 + l4 * 4;
      const int c = n0 + wn * 64 + j * 16 + l15;
      const float bias = (c < 128) ? pbk[c] : (c < 256) ? pbq[c - 128] : pbv[c - 256];
      unsigned short o[4];
      #pragma unroll
      for (int r = 0; r < 4; ++r) o[r] = f2bf(acc[i][j][r] + bias);
      if (c < 128) {
        #pragma unroll
        for (int r = 0; r < 4; ++r) kb[(size_t)(rbase + r) * 128 + c] = o[r];
      } else if (c < 256) {
        ushort4 t; t.x = o[0]; t.y = o[1]; t.z = o[2]; t.w = o[3];
        *(ushort4*)(qtb + (size_t)(c - 128) * 8192 + rbase) = t;
      } else {
        #pragma unroll
        for (int r = 0; r < 4; ++r) vb[(size_t)(rbase + r) * 512 + (c - 256)] = o[r];
        ushort4 t; t.x = o[0]; t.y = o[1]; t.z = o[2]; t.w = o[3];
        *(ushort4*)(vtb + (size_t)(c - 256) * 8192 + rbase) = t;
      }
    }
  }
}

// ---------------- [G|H] = Q^T [Q|V]  (LDS-staged split-K, double-buffered) ----------------
// grid (kc=32 g-chunks of 256, nq=8 col-slices of 80), 512 thr (8 waves).
__global__ __launch_bounds__(512) void gh_gemm(
    const unsigned short* __restrict__ qtb, const unsigned short* __restrict__ vtb,
    unsigned short* __restrict__ pb)
{
  __shared__ unsigned short Alds[2][128 * 64];  // [m][g] swizzled
  __shared__ unsigned short Blds[2][80 * 64];   // [col][g] swizzled
  const int tid = threadIdx.x, lane = tid & 63, wid = tid >> 6;
  const int l15 = lane & 15, l4 = lane >> 4;
  const int kc = blockIdx.x, nq = blockIdx.y;
  const int g0 = kc * 256;
  const int m0 = wid * 16;

  f32x4 acc[5] = {};

  auto stage = [&](int b, int st) {
    const int gs = g0 + st * 64;
    #pragma unroll
    for (int p = 0; p < 2; ++p) {
      const int e = p * 512 + tid;
      const int row = e >> 3;
      const int cs = (e & 7) ^ (row & 7);
      GLL(qtb + (size_t)row * 8192 + gs + cs * 8, &Alds[b][(p * 512 + (tid & ~63)) * 8]);
    }
    {
      const int row = tid >> 3;
      const int cglob = nq * 80 + row;
      const unsigned short* src = (cglob < 128) ? (qtb + (size_t)cglob * 8192)
                                                : (vtb + (size_t)(cglob - 128) * 8192);
      const int cs = (tid & 7) ^ (row & 7);
      GLL(src + gs + cs * 8, &Blds[b][(tid & ~63) * 8]);
    }
    if (tid < 128) {
      const int e = 512 + tid;
      const int row = e >> 3;
      const int cglob = nq * 80 + row;
      const unsigned short* src = (cglob < 128) ? (qtb + (size_t)cglob * 8192)
                                                : (vtb + (size_t)(cglob - 128) * 8192);
      const int cs = (e & 7) ^ (row & 7);
      GLL(src + gs + cs * 8, &Blds[b][(512 + (tid & ~63)) * 8]);
    }
  };

  stage(0, 0);
  __syncthreads();

  for (int st = 0; st < 4; ++st) {
    const int cur = st & 1;
    if (st < 3) stage(cur ^ 1, st + 1);
    #pragma unroll
    for (int ks = 0; ks < 2; ++ks) {
      const int ra = m0 + l15;
      const int ca = ks * 4 + l4;
      const bf16x8 af = *(const bf16x8*)(&Alds[cur][ra * 64 + ((ca ^ (ra & 7)) * 8)]);
      #pragma unroll
      for (int nf = 0; nf < 5; ++nf) {
        const int rb = nf * 16 + l15;
        const bf16x8 bf = *(const bf16x8*)(&Blds[cur][rb * 64 + ((ca ^ (rb & 7)) * 8)]);
        acc[nf] = __builtin_amdgcn_mfma_f32_16x16x32_bf16(af, bf, acc[nf], 0, 0, 0);
      }
    }
    __syncthreads();
  }

  #pragma unroll
  for (int nf = 0; nf < 5; ++nf) {
    const int col = nq * 80 + nf * 16 + l15;
    #pragma unroll
    for (int r = 0; r < 4; ++r) {
      const int row = m0 + l4 * 4 + r;
      pb[((size_t)kc * 128 + row) * 640 + col] = f2bf(acc[nf][r]);
    }
  }
}

// Sum 32 bf16 partials -> Gb [128][128] bf16, Hbt [512][128] bf16 (H transposed).
__global__ void gh_finalize(const unsigned short* __restrict__ pb,
                            unsigned short* __restrict__ Gb, unsigned short* __restrict__ Hbt) {
  const int idx = blockIdx.x * 256 + threadIdx.x;  // 0..81919
  float s = 0.f;
  #pragma unroll
  for (int p = 0; p < 32; ++p) s += bf2f(pb[(size_t)p * 81920 + idx]);
  const int m = idx / 640, c = idx % 640;
  if (c < 128) Gb[m * 128 + c] = f2bf(s);
  else         Hbt[(size_t)(c - 128) * 128 + m] = f2bf(s);
}

// ---------------- fused: rnorm (k_i G k_i^T) + out = (K·H)*rnorm + v ----------------
// grid 256 blocks of 32 rows; 512 thr; wave w: mf=w&1 (16-row frag), nq=w>>1 (col slice).
__global__ __launch_bounds__(512) void tnorm_uv(
    const unsigned short* __restrict__ kb, const unsigned short* __restrict__ Gb,
    const unsigned short* __restrict__ Hbt, const unsigned short* __restrict__ vb,
    float* __restrict__ out)
{
  __shared__ float ssq_part[4][32];
  __shared__ float rnorm_lds[32];
  const int tid = threadIdx.x, lane = tid & 63, wid = tid >> 6;
  const int l15 = lane & 15, l4 = lane >> 4;
  const int m0 = blockIdx.x * 32;
  const int mf = wid & 1, nq = wid >> 1;
  const int rowbase = m0 + mf * 16;

  // K A-fragments for these 16 rows (shared by both phases)
  bf16x8 af[4];
  #pragma unroll
  for (int ks = 0; ks < 4; ++ks)
    af[ks] = *(const bf16x8*)(kb + (size_t)(rowbase + l15) * 128 + ks * 32 + l4 * 8);

  // ---- phase 1: this wave's 2-column-frag slice of T = K·G, partial rowdot ----
  f32x4 tac[2] = {};
  #pragma unroll
  for (int ks = 0; ks < 4; ++ks) {
    #pragma unroll
    for (int t = 0; t < 2; ++t) {
      const int nf = nq * 2 + t;
      const bf16x8 bf = *(const bf16x8*)(Gb + (size_t)(nf * 16 + l15) * 128 + ks * 32 + l4 * 8);
      tac[t] = __builtin_amdgcn_mfma_f32_16x16x32_bf16(af[ks], bf, tac[t], 0, 0, 0);
    }
  }
  float ssq[4] = {0.f, 0.f, 0.f, 0.f};
  #pragma unroll
  for (int t = 0; t < 2; ++t) {
    const int col = (nq * 2 + t) * 16 + l15;
    #pragma unroll
    for (int r = 0; r < 4; ++r) {
      const int row = rowbase + l4 * 4 + r;
      ssq[r] += tac[t][r] * bf2f(kb[(size_t)row * 128 + col]);
    }
  }
  #pragma unroll
  for (int d = 1; d < 16; d <<= 1)
    #pragma unroll
    for (int r = 0; r < 4; ++r) ssq[r] += __shfl_xor(ssq[r], d);
  if (l15 == 0) {
    #pragma unroll
    for (int r = 0; r < 4; ++r) ssq_part[nq][mf * 16 + l4 * 4 + r] = ssq[r];
  }
  __syncthreads();
  if (tid < 32) {
    const float s = ssq_part[0][tid] + ssq_part[1][tid] + ssq_part[2][tid] + ssq_part[3][tid];
    rnorm_lds[tid] = 1.0f / fmaxf(sqrtf(s), 1e-12f);
  }
  __syncthreads();

  // ---- phase 2: U = K·H for cols [nq*128, +128) ----
  f32x4 acc[8] = {};
  #pragma unroll
  for (int ks = 0; ks < 4; ++ks) {
    #pragma unroll
    for (int nf = 0; nf < 8; ++nf) {
      const int col = nq * 128 + nf * 16 + l15;
      const bf16x8 bf = *(const bf16x8*)(Hbt + (size_t)col * 128 + ks * 32 + l4 * 8);
      acc[nf] = __builtin_amdgcn_mfma_f32_16x16x32_bf16(af[ks], bf, acc[nf], 0, 0, 0);
    }
  }

  float rn[4];
  #pragma unroll
  for (int r = 0; r < 4; ++r) rn[r] = rnorm_lds[mf * 16 + l4 * 4 + r];

  #pragma unroll
  for (int nf = 0; nf < 8; ++nf) {
    const int col = nq * 128 + nf * 16 + l15;
    #pragma unroll
    for (int r = 0; r < 4; ++r) {
      const int row = rowbase + l4 * 4 + r;
      out[(size_t)row * 512 + col] =
          acc[nf][r] * rn[r] + bf2f(vb[(size_t)row * 512 + col]);
    }
  }
}

extern "C" void kernel_launch(void* const* d_in, const int* in_sizes, int n_in,
                              void* d_out, int out_size, void* d_ws, size_t ws_size,
                              hipStream_t stream) {
  const float* x  = (const float*)d_in[0];
  const float* Wk = (const float*)d_in[1];
  const float* bk = (const float*)d_in[2];
  const float* Wq = (const float*)d_in[3];
  const float* bq = (const float*)d_in[4];
  const float* Wv = (const float*)d_in[5];
  const float* bv = (const float*)d_in[6];
  float* out = (float*)d_out;

  char* ws = (char*)d_ws;
  unsigned short* xb   = (unsigned short*)(ws);              //  8192*512*2 = 8,388,608
  unsigned short* wb   = (unsigned short*)(ws + 8388608);    //   768*512*2 =   786,432
  unsigned short* kb   = (unsigned short*)(ws + 9175040);    //  8192*128*2 = 2,097,152
  unsigned short* vb   = (unsigned short*)(ws + 11272192);   //  8192*512*2 = 8,388,608
  unsigned short* vtb  = (unsigned short*)(ws + 19660800);   //   512*8192*2= 8,388,608
  unsigned short* qtb  = (unsigned short*)(ws + 28049408);   //   128*8192*2= 2,097,152
  unsigned short* pb   = (unsigned short*)(ws + 30146560);   //  32*128*640*2=5,242,880
  unsigned short* Gb   = (unsigned short*)(ws + 35389440);   //   128*128*2 =    32,768
  unsigned short* Hbt  = (unsigned short*)(ws + 35422208);   //   512*128*2 =   131,072

  cvt_all<<<4480, 256, 0, stream>>>(x, Wk, Wq, Wv, xb, wb);
  qkv_gemm<<<dim3(64, 6), 256, 0, stream>>>(xb, wb, bk, bq, bv, kb, qtb, vb, vtb);
  gh_gemm<<<dim3(32, 8), 512, 0, stream>>>(qtb, vtb, pb);
  gh_finalize<<<320, 256, 0, stream>>>(pb, Gb, Hbt);
  tnorm_uv<<<256, 512, 0, stream>>>(kb, Gb, Hbt, vb, out);
}

// Round 5
// 52.369 us; speedup vs baseline: 6.7203x; 1.0164x over previous
//
#include <hip/hip_runtime.h>
#include <hip/hip_bf16.h>
#include <stdint.h>

typedef __attribute__((ext_vector_type(8))) short bf16x8;
typedef __attribute__((ext_vector_type(4))) float f32x4;

__device__ __forceinline__ unsigned short f2bf(float f) {
  union { float f; uint32_t u; } v; v.f = f;
  uint32_t u = v.u;
  return (unsigned short)((u + 0x7fffu + ((u >> 16) & 1u)) >> 16);
}
__device__ __forceinline__ float bf2f(unsigned short h) {
  union { uint32_t u; float f; } v; v.u = ((uint32_t)h) << 16;
  return v.f;
}

#define GLL(g, l) __builtin_amdgcn_global_load_lds( \
    (const __attribute__((address_space(1))) void*)(g), \
    (__attribute__((address_space(3))) void*)(l), 16, 0, 0)

// ---------------- fp32 -> bf16 convert (x and Wk|Wq|Wv in one launch) ----------------
__global__ void cvt_all(const float* __restrict__ x,
                        const float* __restrict__ wk, const float* __restrict__ wq,
                        const float* __restrict__ wv,
                        unsigned short* __restrict__ xb, unsigned short* __restrict__ wb) {
  const int i = (blockIdx.x * 256 + threadIdx.x) * 4;
  const float* src; unsigned short* dst; int off;
  if (i < 4194304) { src = x; dst = xb; off = i; }
  else {
    const int j = i - 4194304;
    if (j < 65536)       { src = wk; off = j; }
    else if (j < 131072) { src = wq; off = j - 65536; }
    else                 { src = wv; off = j - 131072; }
    dst = wb + (j - off);
  }
  const float4 v = *(const float4*)(src + off);
  ushort4 o; o.x = f2bf(v.x); o.y = f2bf(v.y); o.z = f2bf(v.z); o.w = f2bf(v.w);
  *(ushort4*)(dst + off) = o;
}

// ---------------- QKV projection GEMM: C[m,n] = x[m,:]·W[n,:] + b[n] ----------------
// 64x128 tile, BK=64, 4 waves (2m x 2n), dbuf LDS (48 KB -> 3 blocks/CU), XCD-chunked grid.
__global__ __launch_bounds__(256, 3) void qkv_gemm(
    const unsigned short* __restrict__ xb, const unsigned short* __restrict__ wb,
    const float* __restrict__ pbk, const float* __restrict__ pbq, const float* __restrict__ pbv,
    unsigned short* __restrict__ kb, unsigned short* __restrict__ qtb,
    unsigned short* __restrict__ vb, unsigned short* __restrict__ vtb)
{
  __shared__ unsigned short Alds[2][64 * 64];
  __shared__ unsigned short Blds[2][128 * 64];
  const int tid = threadIdx.x;
  const int lane = tid & 63;
  const int wid = tid >> 6;
  const int wm = wid >> 1, wn = wid & 1;
  // bijective XCD-chunk swizzle: 768 blocks = 8 XCDs x 96 contiguous
  const int wg = blockIdx.x;
  const int s = (wg & 7) * 96 + (wg >> 3);
  const int bx = s & 127, by = s >> 7;       // bx: 0..127 (m), by: 0..5 (n)
  const int m0 = bx * 64, n0 = by * 128;
  const int l15 = lane & 15, l4 = lane >> 4;

  f32x4 acc[2][4] = {};

  auto stage = [&](int b, int kt) {
    const int k0 = kt * 64;
    #pragma unroll
    for (int p = 0; p < 2; ++p) {                 // A: 64 rows x 64 cols
      const int e = p * 256 + tid;
      const int row = e >> 3;
      const int cs = (e & 7) ^ (row & 7);
      GLL(xb + (size_t)(m0 + row) * 512 + k0 + cs * 8, &Alds[b][(p * 256 + (tid & ~63)) * 8]);
    }
    #pragma unroll
    for (int p = 0; p < 4; ++p) {                 // B: 128 rows x 64 cols
      const int e = p * 256 + tid;
      const int row = e >> 3;
      const int cs = (e & 7) ^ (row & 7);
      GLL(wb + (size_t)(n0 + row) * 512 + k0 + cs * 8, &Blds[b][(p * 256 + (tid & ~63)) * 8]);
    }
  };

  stage(0, 0);
  __syncthreads();

  for (int kt = 0; kt < 8; ++kt) {
    const int cur = kt & 1;
    if (kt < 7) stage(cur ^ 1, kt + 1);  // async loads overlap compute below
    #pragma unroll
    for (int kk = 0; kk < 2; ++kk) {
      bf16x8 af[2], bfv[4];
      #pragma unroll
      for (int i = 0; i < 2; ++i) {
        const int ra = wm * 32 + i * 16 + l15;
        const int c  = kk * 4 + l4;
        af[i] = *(const bf16x8*)(&Alds[cur][ra * 64 + ((c ^ (ra & 7)) * 8)]);
      }
      #pragma unroll
      for (int j = 0; j < 4; ++j) {
        const int rb = wn * 64 + j * 16 + l15;
        const int c  = kk * 4 + l4;
        bfv[j] = *(const bf16x8*)(&Blds[cur][rb * 64 + ((c ^ (rb & 7)) * 8)]);
      }
      #pragma unroll
      for (int i = 0; i < 2; ++i)
        #pragma unroll
        for (int j = 0; j < 4; ++j)
          acc[i][j] = __builtin_amdgcn_mfma_f32_16x16x32_bf16(af[i], bfv[j], acc[i][j], 0, 0, 0);
    }
    __syncthreads();
  }

  #pragma unroll
  for (int i = 0; i < 2; ++i) {
    #pragma unroll
    for (int j = 0; j < 4; ++j) {
      const int rbase = m0 + wm * 32 + i * 16 + l4 * 4;
      const int c = n0 + wn * 64 + j * 16 + l15;
      const float bias = (c < 128) ? pbk[c] : (c < 256) ? pbq[c - 128] : pbv[c - 256];
      unsigned short o[4];
      #pragma unroll
      for (int r = 0; r < 4; ++r) o[r] = f2bf(acc[i][j][r] + bias);
      if (c < 128) {
        #pragma unroll
        for (int r = 0; r < 4; ++r) kb[(size_t)(rbase + r) * 128 + c] = o[r];
      } else if (c < 256) {
        ushort4 t; t.x = o[0]; t.y = o[1]; t.z = o[2]; t.w = o[3];
        *(ushort4*)(qtb + (size_t)(c - 128) * 8192 + rbase) = t;
      } else {
        #pragma unroll
        for (int r = 0; r < 4; ++r) vb[(size_t)(rbase + r) * 512 + (c - 256)] = o[r];
        ushort4 t; t.x = o[0]; t.y = o[1]; t.z = o[2]; t.w = o[3];
        *(ushort4*)(vtb + (size_t)(c - 256) * 8192 + rbase) = t;
      }
    }
  }
}

// ---------------- [G|H] = Q^T [Q|V]  (LDS-staged split-K, double-buffered) ----------------
// grid (kc=32 g-chunks of 256, nq=8 col-slices of 80), 512 thr (8 waves).
__global__ __launch_bounds__(512) void gh_gemm(
    const unsigned short* __restrict__ qtb, const unsigned short* __restrict__ vtb,
    unsigned short* __restrict__ pb)
{
  __shared__ unsigned short Alds[2][128 * 64];  // [m][g] swizzled
  __shared__ unsigned short Blds[2][80 * 64];   // [col][g] swizzled
  const int tid = threadIdx.x, lane = tid & 63, wid = tid >> 6;
  const int l15 = lane & 15, l4 = lane >> 4;
  const int kc = blockIdx.x, nq = blockIdx.y;
  const int g0 = kc * 256;
  const int m0 = wid * 16;

  f32x4 acc[5] = {};

  auto stage = [&](int b, int st) {
    const int gs = g0 + st * 64;
    #pragma unroll
    for (int p = 0; p < 2; ++p) {
      const int e = p * 512 + tid;
      const int row = e >> 3;
      const int cs = (e & 7) ^ (row & 7);
      GLL(qtb + (size_t)row * 8192 + gs + cs * 8, &Alds[b][(p * 512 + (tid & ~63)) * 8]);
    }
    {
      const int row = tid >> 3;
      const int cglob = nq * 80 + row;
      const unsigned short* src = (cglob < 128) ? (qtb + (size_t)cglob * 8192)
                                                : (vtb + (size_t)(cglob - 128) * 8192);
      const int cs = (tid & 7) ^ (row & 7);
      GLL(src + gs + cs * 8, &Blds[b][(tid & ~63) * 8]);
    }
    if (tid < 128) {
      const int e = 512 + tid;
      const int row = e >> 3;
      const int cglob = nq * 80 + row;
      const unsigned short* src = (cglob < 128) ? (qtb + (size_t)cglob * 8192)
                                                : (vtb + (size_t)(cglob - 128) * 8192);
      const int cs = (e & 7) ^ (row & 7);
      GLL(src + gs + cs * 8, &Blds[b][(512 + (tid & ~63)) * 8]);
    }
  };

  stage(0, 0);
  __syncthreads();

  for (int st = 0; st < 4; ++st) {
    const int cur = st & 1;
    if (st < 3) stage(cur ^ 1, st + 1);
    #pragma unroll
    for (int ks = 0; ks < 2; ++ks) {
      const int ra = m0 + l15;
      const int ca = ks * 4 + l4;
      const bf16x8 af = *(const bf16x8*)(&Alds[cur][ra * 64 + ((ca ^ (ra & 7)) * 8)]);
      #pragma unroll
      for (int nf = 0; nf < 5; ++nf) {
        const int rb = nf * 16 + l15;
        const bf16x8 bf = *(const bf16x8*)(&Blds[cur][rb * 64 + ((ca ^ (rb & 7)) * 8)]);
        acc[nf] = __builtin_amdgcn_mfma_f32_16x16x32_bf16(af, bf, acc[nf], 0, 0, 0);
      }
    }
    __syncthreads();
  }

  #pragma unroll
  for (int nf = 0; nf < 5; ++nf) {
    const int col = nq * 80 + nf * 16 + l15;
    #pragma unroll
    for (int r = 0; r < 4; ++r) {
      const int row = m0 + l4 * 4 + r;
      pb[((size_t)kc * 128 + row) * 640 + col] = f2bf(acc[nf][r]);
    }
  }
}

// Sum 32 bf16 partials -> Gb [128][128] bf16, Hbt [512][128] bf16 (H transposed).
__global__ void gh_finalize(const unsigned short* __restrict__ pb,
                            unsigned short* __restrict__ Gb, unsigned short* __restrict__ Hbt) {
  const int idx = blockIdx.x * 256 + threadIdx.x;  // 0..81919
  float s = 0.f;
  #pragma unroll
  for (int p = 0; p < 32; ++p) s += bf2f(pb[(size_t)p * 81920 + idx]);
  const int m = idx / 640, c = idx % 640;
  if (c < 128) Gb[m * 128 + c] = f2bf(s);
  else         Hbt[(size_t)(c - 128) * 128 + m] = f2bf(s);
}

// ---------------- fused: rnorm (k_i G k_i^T) + out = (K·H)*rnorm + v ----------------
// grid 512 blocks of 16 rows; 512 thr (8 waves); wave w: G-frag w (phase1), H cols [w*64,+64) (phase2).
__global__ __launch_bounds__(512) void tnorm_uv(
    const unsigned short* __restrict__ kb, const unsigned short* __restrict__ Gb,
    const unsigned short* __restrict__ Hbt, const unsigned short* __restrict__ vb,
    float* __restrict__ out)
{
  __shared__ float ssq_part[8][16];
  __shared__ float rnorm_lds[16];
  const int tid = threadIdx.x, lane = tid & 63, wid = tid >> 6;
  const int l15 = lane & 15, l4 = lane >> 4;
  const int rowbase = blockIdx.x * 16;

  // K A-fragments for these 16 rows (shared by both phases)
  bf16x8 af[4];
  #pragma unroll
  for (int ks = 0; ks < 4; ++ks)
    af[ks] = *(const bf16x8*)(kb + (size_t)(rowbase + l15) * 128 + ks * 32 + l4 * 8);

  // ---- phase 1: T-frag (cols wid*16..+16) of T = K·G, partial rowdot ----
  f32x4 tac = {};
  #pragma unroll
  for (int ks = 0; ks < 4; ++ks) {
    const bf16x8 bf = *(const bf16x8*)(Gb + (size_t)(wid * 16 + l15) * 128 + ks * 32 + l4 * 8);
    tac = __builtin_amdgcn_mfma_f32_16x16x32_bf16(af[ks], bf, tac, 0, 0, 0);
  }
  float ssq[4];
  #pragma unroll
  for (int r = 0; r < 4; ++r) {
    const int row = rowbase + l4 * 4 + r;
    ssq[r] = tac[r] * bf2f(kb[(size_t)row * 128 + wid * 16 + l15]);
  }
  #pragma unroll
  for (int d = 1; d < 16; d <<= 1)
    #pragma unroll
    for (int r = 0; r < 4; ++r) ssq[r] += __shfl_xor(ssq[r], d);
  if (l15 == 0) {
    #pragma unroll
    for (int r = 0; r < 4; ++r) ssq_part[wid][l4 * 4 + r] = ssq[r];
  }
  __syncthreads();
  if (tid < 16) {
    float s = 0.f;
    #pragma unroll
    for (int w = 0; w < 8; ++w) s += ssq_part[w][tid];
    rnorm_lds[tid] = 1.0f / fmaxf(sqrtf(s), 1e-12f);
  }
  __syncthreads();

  // ---- phase 2: U = K·H for cols [wid*64, +64) ----
  f32x4 acc[4] = {};
  #pragma unroll
  for (int ks = 0; ks < 4; ++ks) {
    #pragma unroll
    for (int nf = 0; nf < 4; ++nf) {
      const int col = wid * 64 + nf * 16 + l15;
      const bf16x8 bf = *(const bf16x8*)(Hbt + (size_t)col * 128 + ks * 32 + l4 * 8);
      acc[nf] = __builtin_amdgcn_mfma_f32_16x16x32_bf16(af[ks], bf, acc[nf], 0, 0, 0);
    }
  }

  float rn[4];
  #pragma unroll
  for (int r = 0; r < 4; ++r) rn[r] = rnorm_lds[l4 * 4 + r];

  #pragma unroll
  for (int nf = 0; nf < 4; ++nf) {
    const int col = wid * 64 + nf * 16 + l15;
    #pragma unroll
    for (int r = 0; r < 4; ++r) {
      const int row = rowbase + l4 * 4 + r;
      out[(size_t)row * 512 + col] =
          acc[nf][r] * rn[r] + bf2f(vb[(size_t)row * 512 + col]);
    }
  }
}

extern "C" void kernel_launch(void* const* d_in, const int* in_sizes, int n_in,
                              void* d_out, int out_size, void* d_ws, size_t ws_size,
                              hipStream_t stream) {
  const float* x  = (const float*)d_in[0];
  const float* Wk = (const float*)d_in[1];
  const float* bk = (const float*)d_in[2];
  const float* Wq = (const float*)d_in[3];
  const float* bq = (const float*)d_in[4];
  const float* Wv = (const float*)d_in[5];
  const float* bv = (const float*)d_in[6];
  float* out = (float*)d_out;

  char* ws = (char*)d_ws;
  unsigned short* xb   = (unsigned short*)(ws);              //  8192*512*2 = 8,388,608
  unsigned short* wb   = (unsigned short*)(ws + 8388608);    //   768*512*2 =   786,432
  unsigned short* kb   = (unsigned short*)(ws + 9175040);    //  8192*128*2 = 2,097,152
  unsigned short* vb   = (unsigned short*)(ws + 11272192);   //  8192*512*2 = 8,388,608
  unsigned short* vtb  = (unsigned short*)(ws + 19660800);   //   512*8192*2= 8,388,608
  unsigned short* qtb  = (unsigned short*)(ws + 28049408);   //   128*8192*2= 2,097,152
  unsigned short* pb   = (unsigned short*)(ws + 30146560);   //  32*128*640*2=5,242,880
  unsigned short* Gb   = (unsigned short*)(ws + 35389440);   //   128*128*2 =    32,768
  unsigned short* Hbt  = (unsigned short*)(ws + 35422208);   //   512*128*2 =   131,072

  cvt_all<<<4480, 256, 0, stream>>>(x, Wk, Wq, Wv, xb, wb);
  qkv_gemm<<<768, 256, 0, stream>>>(xb, wb, bk, bq, bv, kb, qtb, vb, vtb);
  gh_gemm<<<dim3(32, 8), 512, 0, stream>>>(qtb, vtb, pb);
  gh_finalize<<<320, 256, 0, stream>>>(pb, Gb, Hbt);
  tnorm_uv<<<512, 512, 0, stream>>>(kb, Gb, Hbt, vb, out);
}